// Round 15
// baseline (1877.228 us; speedup 1.0000x reference)
//
#include <hip/hip_runtime.h>
#include <hip/hip_bf16.h>
#include <math.h>

#define NNODES 100000
#define NREL 4
#define NEDGE 200000
#define NH 8
#define FDIM 512
#define NMB 782  // ceil(100000/128)

typedef float f4 __attribute__((ext_vector_type(4)));
typedef __bf16 bf16x8 __attribute__((ext_vector_type(8)));
typedef __bf16 bf16x4 __attribute__((ext_vector_type(4)));

__device__ __forceinline__ float eluf(float v) { return v > 0.f ? v : expm1f(v); }
__device__ __forceinline__ void gload16(const __bf16* g, __bf16* l) {
  __builtin_amdgcn_global_load_lds((const __attribute__((address_space(1))) void*)g,
                                   (__attribute__((address_space(3))) void*)l, 16, 0, 0);
}

// ---- f32 -> bf16 convert (count multiple of 1024) ----
__global__ void k_conv(const float* __restrict__ in, __bf16* __restrict__ outp) {
  int i = (blockIdx.x * 256 + threadIdx.x) * 4;
  f4 v = *(const f4*)(in + i);
  bf16x4 o = {(__bf16)v.x, (__bf16)v.y, (__bf16)v.z, (__bf16)v.w};
  *(bf16x4*)(outp + i) = o;
}

// ---- W [4,K,512] f32 -> Wt [4*512, K] bf16 (transposed).
//      permK: apply within-64 K-row permutation k' = (k&15)*4 + ((k>>4)&3)
//      to match the stored (permuted) layout of the A matrix (fbuf/accG). ----
__global__ void k_transW(const float* __restrict__ W, __bf16* __restrict__ Wt, int K,
                         int permK) {
  __shared__ float tile[32][33];
  int r = blockIdx.z;
  const float* Wr = W + (size_t)r * K * FDIM;
  __bf16* Wtr = Wt + (size_t)r * FDIM * K;
  int k0 = blockIdx.x * 32, n0 = blockIdx.y * 32;
  int tx = threadIdx.x, ty = threadIdx.y;
  for (int i = ty; i < 32; i += 8)
    tile[i][tx] = Wr[(size_t)(k0 + i) * FDIM + n0 + tx];
  __syncthreads();
  int kp = k0 + tx;
  int kd = permK ? ((kp & ~63) | ((kp & 15) << 2) | ((kp >> 4) & 3)) : kp;
  for (int i = ty; i < 32; i += 8)
    Wtr[(size_t)(n0 + i) * K + kd] = (__bf16)tile[tx][i];
}

// ---- bf16 MFMA GEMM: BK=64, one barrier per K-tile, 128x128 tile, 2x32KB bufs,
//      XOR-swizzled LDS, bijective XCD swizzle, PERMUTED-LAYOUT packed C store,
//      fused el/er epilogue. C stored col' = (c*4+j) for phys col (c+16j). ----
__global__ __launch_bounds__(256) void k_gemm(const __bf16* __restrict__ A,
                                              const __bf16* __restrict__ BT,
                                              __bf16* __restrict__ C,
                                              const float* __restrict__ al,
                                              const float* __restrict__ ar,
                                              __bf16* __restrict__ el,
                                              __bf16* __restrict__ er, int M, int K) {
  __shared__ alignas(16) __bf16 lds[2][2][128 * 64];
  int t = threadIdx.x, l = t & 63, w = t >> 6;
  int nwg = gridDim.x, q8 = nwg >> 3, r8 = nwg & 7;
  int xx = blockIdx.x & 7, loc = blockIdx.x >> 3;
  int swz = (xx < r8 ? xx * (q8 + 1) : r8 * (q8 + 1) + (xx - r8) * q8) + loc;
  int m0 = (swz >> 2) * 128, n0 = (swz & 3) * 128;
  int wm = (w >> 1) * 64, wn = (w & 1) * 64;
  f4 acc[4][4] = {};

  const __bf16* pSA[4];
  const __bf16* pSB[4];
#pragma unroll
  for (int u = 0; u < 4; u++) {
    int s = t + u * 256;
    int row = s >> 3, c = s & 7;
    int scol = ((c ^ (row & 7)) * 8);
    int ra = m0 + row; if (ra >= M) ra = M - 1;
    pSA[u] = A + (size_t)ra * K + scol;
    pSB[u] = BT + (size_t)(n0 + row) * K + scol;
  }

#define STG(buf, kk)                                          \
  do {                                                        \
    gload16(pSA[0] + (kk), &lds[buf][0][(t) * 8]);            \
    gload16(pSA[1] + (kk), &lds[buf][0][(t + 256) * 8]);      \
    gload16(pSA[2] + (kk), &lds[buf][0][(t + 512) * 8]);      \
    gload16(pSA[3] + (kk), &lds[buf][0][(t + 768) * 8]);      \
    gload16(pSB[0] + (kk), &lds[buf][1][(t) * 8]);            \
    gload16(pSB[1] + (kk), &lds[buf][1][(t + 256) * 8]);      \
    gload16(pSB[2] + (kk), &lds[buf][1][(t + 512) * 8]);      \
    gload16(pSB[3] + (kk), &lds[buf][1][(t + 768) * 8]);      \
  } while (0)

  int rA[4], rB[4];
#pragma unroll
  for (int i = 0; i < 4; i++) {
    rA[i] = (wm + i * 16 + (l & 15)) * 64;
    rB[i] = (wn + i * 16 + (l & 15)) * 64;
  }
  int ch0 = (l >> 4);

  int nt = K >> 6;  // 8 (K=512) or 4 (K=256)
  STG(0, 0);
  for (int kt = 0; kt < nt; kt++) {
    int cb = kt & 1;
    asm volatile("s_waitcnt vmcnt(0)" ::: "memory");
    __builtin_amdgcn_s_barrier();
    __builtin_amdgcn_sched_barrier(0);
    if (kt + 1 < nt) STG(cb ^ 1, (kt + 1) * 64);
    bf16x8 a[4][2], b[4][2];
#pragma unroll
    for (int ks = 0; ks < 2; ks++)
#pragma unroll
      for (int i = 0; i < 4; i++) {
        int ch = ks * 4 + ch0;
        int rowA7 = (rA[i] >> 6) & 7;
        int rowB7 = (rB[i] >> 6) & 7;
        a[i][ks] = *(const bf16x8*)(&lds[cb][0][rA[i] + ((ch ^ rowA7) * 8)]);
        b[i][ks] = *(const bf16x8*)(&lds[cb][1][rB[i] + ((ch ^ rowB7) * 8)]);
      }
#pragma unroll
    for (int ks = 0; ks < 2; ks++)
#pragma unroll
      for (int i = 0; i < 4; i++)
#pragma unroll
        for (int j = 0; j < 4; j++)
          acc[i][j] = __builtin_amdgcn_mfma_f32_16x16x32_bf16(a[i][ks], b[j][ks], acc[i][j], 0, 0, 0);
  }
#undef STG

  // ---- C write: PACKED bf16x4, permuted layout. Stored col' = wn + (l&15)*4 + j
  //      holds phys col wn + (l&15) + j*16 = acc[i][j][q2]. 128B-contig per 16 lanes. ----
  int rbase = m0 + wm + (l >> 4) * 4;
  int cbase = n0 + wn + (l & 15) * 4;
#pragma unroll
  for (int i = 0; i < 4; i++)
#pragma unroll
    for (int q2 = 0; q2 < 4; q2++) {
      int row = rbase + i * 16 + q2;
      if (row < M) {
        bf16x4 o = {(__bf16)acc[i][0][q2], (__bf16)acc[i][1][q2],
                    (__bf16)acc[i][2][q2], (__bf16)acc[i][3][q2]};
        *(bf16x4*)(&C[(size_t)row * FDIM + cbase]) = o;
      }
    }

  // ---- fused el/er (bf16 out): in-register, phys al/ar — unaffected by layout ----
  int h = (n0 + wn) >> 6;
  float av[4], bv[4];
#pragma unroll
  for (int j = 0; j < 4; j++) {
    av[j] = al[h * 64 + j * 16 + (l & 15)];
    bv[j] = ar[h * 64 + j * 16 + (l & 15)];
  }
#pragma unroll
  for (int i = 0; i < 4; i++)
#pragma unroll
    for (int q2 = 0; q2 < 4; q2++) {
      float se = acc[i][0][q2] * av[0] + acc[i][1][q2] * av[1] +
                 acc[i][2][q2] * av[2] + acc[i][3][q2] * av[3];
      float sr = acc[i][0][q2] * bv[0] + acc[i][1][q2] * bv[1] +
                 acc[i][2][q2] * bv[2] + acc[i][3][q2] * bv[3];
      se += __shfl_xor(se, 1); se += __shfl_xor(se, 2);
      se += __shfl_xor(se, 4); se += __shfl_xor(se, 8);
      sr += __shfl_xor(sr, 1); sr += __shfl_xor(sr, 2);
      sr += __shfl_xor(sr, 4); sr += __shfl_xor(sr, 8);
      if ((l & 15) == 0) {
        int row = rbase + i * 16 + q2;
        if (row < M) {
          el[row * NH + h] = (__bf16)se;
          er[row * NH + h] = (__bf16)sr;
        }
      }
    }
}

// ---- CSR build ----
__global__ void k_count(const int* __restrict__ dst, int* __restrict__ deg) {
  int e = blockIdx.x * 256 + threadIdx.x;
  int r = blockIdx.y;
  if (e < NEDGE) {
    int d = dst[(size_t)r * NEDGE + e];
    if ((unsigned)d < (unsigned)NNODES) atomicAdd(&deg[r * NNODES + d], 1);
  }
}

__global__ __launch_bounds__(256) void k_scan_a(const int* __restrict__ in, int* __restrict__ out,
                                                int* __restrict__ bsum, int n) {
  __shared__ int wsums[4];
  int t = threadIdx.x, lane = t & 63, w = t >> 6;
  int base = blockIdx.x * 1024 + t * 4;
  int v0 = base + 0 < n ? in[base + 0] : 0;
  int v1 = base + 1 < n ? in[base + 1] : 0;
  int v2 = base + 2 < n ? in[base + 2] : 0;
  int v3 = base + 3 < n ? in[base + 3] : 0;
  int tot = v0 + v1 + v2 + v3;
  int sc = tot;
#pragma unroll
  for (int off = 1; off < 64; off <<= 1) {
    int u = __shfl_up(sc, off);
    if (lane >= off) sc += u;
  }
  if (lane == 63) wsums[w] = sc;
  __syncthreads();
  int add = 0;
#pragma unroll
  for (int i = 0; i < 4; i++)
    if (i < w) add += wsums[i];
  int excl = add + sc - tot;
  if (base + 0 < n) out[base + 0] = excl;
  if (base + 1 < n) out[base + 1] = excl + v0;
  if (base + 2 < n) out[base + 2] = excl + v0 + v1;
  if (base + 3 < n) out[base + 3] = excl + v0 + v1 + v2;
  if (t == 255) bsum[blockIdx.x] = add + sc;
}

__global__ __launch_bounds__(256) void k_scan_b(int* __restrict__ bsum, int nb) {
  __shared__ int wsums[4];
  int t = threadIdx.x, lane = t & 63, w = t >> 6;
  int i0 = t * 2, i1 = t * 2 + 1;
  int v0 = i0 < nb ? bsum[i0] : 0;
  int v1 = i1 < nb ? bsum[i1] : 0;
  int tot = v0 + v1, sc = tot;
#pragma unroll
  for (int off = 1; off < 64; off <<= 1) {
    int u = __shfl_up(sc, off);
    if (lane >= off) sc += u;
  }
  if (lane == 63) wsums[w] = sc;
  __syncthreads();
  int add = 0;
#pragma unroll
  for (int i = 0; i < 4; i++)
    if (i < w) add += wsums[i];
  int excl = add + sc - tot;
  if (i0 < nb) bsum[i0] = excl;
  if (i1 < nb) bsum[i1] = excl + v0;
}

__global__ void k_scan_c(int* __restrict__ out, const int* __restrict__ bsum, int n) {
  int i = blockIdx.x * 256 + threadIdx.x;
  if (i < n) out[i] += bsum[i >> 10];
}

__global__ void k_scatter(const int* __restrict__ src, const int* __restrict__ dst,
                          const int* __restrict__ ptrf, int* __restrict__ cur,
                          int* __restrict__ csrc) {
  int e = blockIdx.x * 256 + threadIdx.x;
  int r = blockIdx.y;
  if (e >= NEDGE) return;
  int d = dst[(size_t)r * NEDGE + e];
  if ((unsigned)d >= (unsigned)NNODES) return;
  int slot = ptrf[r * NNODES + d] + atomicAdd(&cur[r * NNODES + d], 1);
  if ((unsigned)slot < (unsigned)(NREL * NEDGE))
    csrc[slot] = src[(size_t)r * NEDGE + e];
}

// ---- fused segment-softmax + aggregate + ELU (elementwise in stored-col space),
//      edge-unroll-2; writeMode=1: full write ----
__global__ void k_agg(const __bf16* __restrict__ f, const __bf16* __restrict__ el,
                      const __bf16* __restrict__ er, const int* __restrict__ ptrf,
                      const int* __restrict__ deg, const int* __restrict__ csrc,
                      __bf16* __restrict__ accG, int writeMode) {
  int t = threadIdx.x;
  int l = t & 63;
  int d = blockIdx.x * 4 + (t >> 6);
  int h = l >> 3;
  int cnt = deg[d];
  float res[8] = {0.f, 0.f, 0.f, 0.f, 0.f, 0.f, 0.f, 0.f};
  if (cnt > 0) {
    int start = ptrf[d];
    if (start < 0) start = 0;
    if (start > NREL * NEDGE) start = NREL * NEDGE;
    if (cnt > NREL * NEDGE - start) cnt = NREL * NEDGE - start;
    float erh = (float)er[d * NH + h];
    float a0[8] = {0.f, 0.f, 0.f, 0.f, 0.f, 0.f, 0.f, 0.f};
    float a1[8] = {0.f, 0.f, 0.f, 0.f, 0.f, 0.f, 0.f, 0.f};
    float den = 0.f;
    int j = 0;
    for (; j + 1 < cnt; j += 2) {
      int s0 = csrc[start + j], s1 = csrc[start + j + 1];
      if ((unsigned)s0 >= (unsigned)NNODES) s0 = 0;
      if ((unsigned)s1 >= (unsigned)NNODES) s1 = 0;
      bf16x8 fv0 = *(const bf16x8*)(f + (size_t)s0 * FDIM + l * 8);
      bf16x8 fv1 = *(const bf16x8*)(f + (size_t)s1 * FDIM + l * 8);
      float e0 = (float)el[s0 * NH + h] + erh;
      float e1 = (float)el[s1 * NH + h] + erh;
      e0 = (e0 > 0.f) ? e0 : 0.2f * e0;
      e1 = (e1 > 0.f) ? e1 : 0.2f * e1;
      float ex0 = __expf(e0), ex1 = __expf(e1);
      den += ex0 + ex1;
#pragma unroll
      for (int i = 0; i < 8; i++) {
        a0[i] += ex0 * (float)fv0[i];
        a1[i] += ex1 * (float)fv1[i];
      }
    }
    if (j < cnt) {
      int s0 = csrc[start + j];
      if ((unsigned)s0 >= (unsigned)NNODES) s0 = 0;
      bf16x8 fv0 = *(const bf16x8*)(f + (size_t)s0 * FDIM + l * 8);
      float e0 = (float)el[s0 * NH + h] + erh;
      e0 = (e0 > 0.f) ? e0 : 0.2f * e0;
      float ex0 = __expf(e0);
      den += ex0;
#pragma unroll
      for (int i = 0; i < 8; i++) a0[i] += ex0 * (float)fv0[i];
    }
    float inv = 1.f / (den + 1e-9f);
#pragma unroll
    for (int i = 0; i < 8; i++) res[i] = eluf((a0[i] + a1[i]) * inv);
  } else if (!writeMode) {
    return;
  }
  __bf16* ap = accG + (size_t)d * FDIM + l * 8;
  bf16x8 o;
  if (writeMode) {
#pragma unroll
    for (int i = 0; i < 8; i++) o[i] = (__bf16)res[i];
  } else {
    bf16x8 cv = *(bf16x8*)ap;
#pragma unroll
    for (int i = 0; i < 8; i++) o[i] = (__bf16)((float)cv[i] + res[i]);
  }
  *(bf16x8*)ap = o;
}

// ---- layer-2 agg + fused head-mean; un-permutes stored cols at final out write ----
__global__ void k_aggm(const __bf16* __restrict__ f, const __bf16* __restrict__ el,
                       const __bf16* __restrict__ er, const int* __restrict__ ptrf,
                       const int* __restrict__ deg, const int* __restrict__ csrc,
                       float* __restrict__ out, int writeMode) {
  int t = threadIdx.x;
  int l = t & 63;
  int d = blockIdx.x * 4 + (t >> 6);
  int h = l >> 3;
  int cnt = deg[d];
  float res[8] = {0.f, 0.f, 0.f, 0.f, 0.f, 0.f, 0.f, 0.f};
  if (cnt > 0) {
    int start = ptrf[d];
    if (start < 0) start = 0;
    if (start > NREL * NEDGE) start = NREL * NEDGE;
    if (cnt > NREL * NEDGE - start) cnt = NREL * NEDGE - start;
    float erh = (float)er[d * NH + h];
    float a0[8] = {0.f, 0.f, 0.f, 0.f, 0.f, 0.f, 0.f, 0.f};
    float a1[8] = {0.f, 0.f, 0.f, 0.f, 0.f, 0.f, 0.f, 0.f};
    float den = 0.f;
    int j = 0;
    for (; j + 1 < cnt; j += 2) {
      int s0 = csrc[start + j], s1 = csrc[start + j + 1];
      if ((unsigned)s0 >= (unsigned)NNODES) s0 = 0;
      if ((unsigned)s1 >= (unsigned)NNODES) s1 = 0;
      bf16x8 fv0 = *(const bf16x8*)(f + (size_t)s0 * FDIM + l * 8);
      bf16x8 fv1 = *(const bf16x8*)(f + (size_t)s1 * FDIM + l * 8);
      float e0 = (float)el[s0 * NH + h] + erh;
      float e1 = (float)el[s1 * NH + h] + erh;
      e0 = (e0 > 0.f) ? e0 : 0.2f * e0;
      e1 = (e1 > 0.f) ? e1 : 0.2f * e1;
      float ex0 = __expf(e0), ex1 = __expf(e1);
      den += ex0 + ex1;
#pragma unroll
      for (int i = 0; i < 8; i++) {
        a0[i] += ex0 * (float)fv0[i];
        a1[i] += ex1 * (float)fv1[i];
      }
    }
    if (j < cnt) {
      int s0 = csrc[start + j];
      if ((unsigned)s0 >= (unsigned)NNODES) s0 = 0;
      bf16x8 fv0 = *(const bf16x8*)(f + (size_t)s0 * FDIM + l * 8);
      float e0 = (float)el[s0 * NH + h] + erh;
      e0 = (e0 > 0.f) ? e0 : 0.2f * e0;
      float ex0 = __expf(e0);
      den += ex0;
#pragma unroll
      for (int i = 0; i < 8; i++) a0[i] += ex0 * (float)fv0[i];
    }
    float inv = 1.f / (den + 1e-9f);
#pragma unroll
    for (int i = 0; i < 8; i++) res[i] = eluf((a0[i] + a1[i]) * inv);
  }
  // cross-head sum (heads are bits 3-5 of l; within-head position is stored-space)
#pragma unroll
  for (int i = 0; i < 8; i++) {
    res[i] += __shfl_xor(res[i], 8);
    res[i] += __shfl_xor(res[i], 16);
    res[i] += __shfl_xor(res[i], 32);
  }
  if (l < 8) {
#pragma unroll
    for (int i = 0; i < 8; i++) {
      int sw = l * 8 + i;                       // stored within-head col
      int p = (sw >> 2) + (sw & 3) * 16;        // phys within-head col
      float v = res[i] * 0.125f;
      if (writeMode) out[(size_t)d * 64 + p] = v;
      else           out[(size_t)d * 64 + p] += v;
    }
  }
}

// ---- host ----
extern "C" void kernel_launch(void* const* d_in, const int* in_sizes, int n_in,
                              void* d_out, int out_size, void* d_ws, size_t ws_size,
                              hipStream_t stream) {
  const float* x = (const float*)d_in[0];
  const int* srcp = (const int*)d_in[1];
  const int* dstp = (const int*)d_in[2];
  const float* Wl[3]  = {(const float*)d_in[3], (const float*)d_in[6], (const float*)d_in[9]};
  const float* alp[3] = {(const float*)d_in[4], (const float*)d_in[7], (const float*)d_in[10]};
  const float* arl[3] = {(const float*)d_in[5], (const float*)d_in[8], (const float*)d_in[11]};
  float* out = (float*)d_out;
  (void)in_sizes; (void)n_in; (void)out_size;

  auto rup = [](size_t b) { return (b + 255) & ~(size_t)255; };
  size_t need = 3 * rup((size_t)NNODES * FDIM * 2) +
                2 * rup((size_t)NNODES * NH * 2) +
                rup((size_t)NREL * FDIM * FDIM * 2) +
                2 * rup((size_t)NREL * NNODES * 4) +
                rup((size_t)NREL * NEDGE * 4);
  if (ws_size < need) return;

  char* ws = (char*)d_ws;
  size_t off = 0;
  auto alloc = [&](size_t bytes) -> void* { void* p = ws + off; off += rup(bytes); return p; };
  __bf16* b0   = (__bf16*)alloc((size_t)NNODES * FDIM * 2);
  __bf16* b1   = (__bf16*)alloc((size_t)NNODES * FDIM * 2);
  __bf16* fbuf = (__bf16*)alloc((size_t)NNODES * FDIM * 2);
  __bf16* el   = (__bf16*)alloc((size_t)NNODES * NH * 2);
  __bf16* er   = (__bf16*)alloc((size_t)NNODES * NH * 2);
  __bf16* Wt   = (__bf16*)alloc((size_t)NREL * FDIM * FDIM * 2);
  int* deg  = (int*)alloc((size_t)NREL * NNODES * 4);
  int* ptrf = (int*)alloc((size_t)NREL * NNODES * 4);
  int* csrc = (int*)alloc((size_t)NREL * NEDGE * 4);
  int* cur  = (int*)fbuf;
  int* bsum = (int*)((char*)fbuf + rup((size_t)NREL * NNODES * 4));

  // ---- CSR by dst ----
  hipMemsetAsync(deg, 0, (size_t)NREL * NNODES * 4, stream);
  hipMemsetAsync(cur, 0, (size_t)NREL * NNODES * 4, stream);
  k_count<<<dim3((NEDGE + 255) / 256, NREL), 256, 0, stream>>>(dstp, deg);
  int ntot = NREL * NNODES;
  int nb1 = (ntot + 1023) / 1024;
  k_scan_a<<<nb1, 256, 0, stream>>>(deg, ptrf, bsum, ntot);
  k_scan_b<<<1, 256, 0, stream>>>(bsum, nb1);
  k_scan_c<<<(ntot + 255) / 256, 256, 0, stream>>>(ptrf, bsum, ntot);
  k_scatter<<<dim3((NEDGE + 255) / 256, NREL), 256, 0, stream>>>(srcp, dstp, ptrf, cur, csrc);

  // layer-0 input: conv x -> b1 as [N,256] bf16 (natural col order)
  k_conv<<<(NNODES * 256) / 1024, 256, 0, stream>>>(x, b1);

  int ngrid = NMB * 4;  // 3128 (128x128 tiles over [100000, 512])
  for (int L = 0; L < 3; L++) {
    int K = (L == 0) ? 256 : FDIM;
    const __bf16* inb = (L == 1) ? b0 : b1;  // L0:b1(x), L1:b0, L2:b1
    __bf16* outb = (L == 0) ? b0 : b1;       // L2 writes d_out instead
    // layers 1-2: A (= accG from previous layer) is stored-permuted -> permute W's K rows
    k_transW<<<dim3(K / 32, 16, NREL), dim3(32, 8), 0, stream>>>(Wl[L], Wt, K, L > 0 ? 1 : 0);
    for (int r = 0; r < NREL; r++) {
      k_gemm<<<ngrid, 256, 0, stream>>>(inb, Wt + (size_t)r * FDIM * K, fbuf,
                                        alp[L] + (size_t)r * 512,
                                        arl[L] + (size_t)r * 512,
                                        el, er, NNODES, K);
      if (L < 2)
        k_agg<<<NNODES / 4, 256, 0, stream>>>(fbuf, el, er, ptrf + (size_t)r * NNODES,
                                              deg + (size_t)r * NNODES, csrc, outb,
                                              r == 0 ? 1 : 0);
      else
        k_aggm<<<NNODES / 4, 256, 0, stream>>>(fbuf, el, er, ptrf + (size_t)r * NNODES,
                                               deg + (size_t)r * NNODES, csrc, out,
                                               r == 0 ? 1 : 0);
    }
  }
}

// Round 16
// 1854.163 us; speedup vs baseline: 1.0124x; 1.0124x over previous
//
#include <hip/hip_runtime.h>
#include <hip/hip_bf16.h>
#include <math.h>

#define NNODES 100000
#define NREL 4
#define NEDGE 200000
#define NH 8
#define FDIM 512
#define NMB 782  // ceil(100000/128)

typedef float f4 __attribute__((ext_vector_type(4)));
typedef float f2 __attribute__((ext_vector_type(2)));
typedef __bf16 bf16x8 __attribute__((ext_vector_type(8)));
typedef __bf16 bf16x4 __attribute__((ext_vector_type(4)));

__device__ __forceinline__ float eluf(float v) { return v > 0.f ? v : expm1f(v); }
__device__ __forceinline__ void gload16(const __bf16* g, __bf16* l) {
  __builtin_amdgcn_global_load_lds((const __attribute__((address_space(1))) void*)g,
                                   (__attribute__((address_space(3))) void*)l, 16, 0, 0);
}

// ---- f32 -> bf16 convert (count multiple of 1024) ----
__global__ void k_conv(const float* __restrict__ in, __bf16* __restrict__ outp) {
  int i = (blockIdx.x * 256 + threadIdx.x) * 4;
  f4 v = *(const f4*)(in + i);
  bf16x4 o = {(__bf16)v.x, (__bf16)v.y, (__bf16)v.z, (__bf16)v.w};
  *(bf16x4*)(outp + i) = o;
}

// ---- W [4,K,512] f32 -> Wt [4*512, K] bf16 (transposed).
//      permK: within-64 K-row permutation k' = (k&15)*4 + ((k>>4)&3) to match
//      the stored (permuted) layout of fbuf/accG from the previous layer. ----
__global__ void k_transW(const float* __restrict__ W, __bf16* __restrict__ Wt, int K,
                         int permK) {
  __shared__ float tile[32][33];
  int r = blockIdx.z;
  const float* Wr = W + (size_t)r * K * FDIM;
  __bf16* Wtr = Wt + (size_t)r * FDIM * K;
  int k0 = blockIdx.x * 32, n0 = blockIdx.y * 32;
  int tx = threadIdx.x, ty = threadIdx.y;
  for (int i = ty; i < 32; i += 8)
    tile[i][tx] = Wr[(size_t)(k0 + i) * FDIM + n0 + tx];
  __syncthreads();
  int kp = k0 + tx;
  int kd = permK ? ((kp & ~63) | ((kp & 15) << 2) | ((kp >> 4) & 3)) : kp;
  for (int i = ty; i < 32; i += 8)
    Wtr[(size_t)(n0 + i) * K + kd] = (__bf16)tile[tx][i];
}

// ---- bf16 MFMA GEMM: BK=64, one barrier per K-tile, 128x128 tile, 2x32KB bufs,
//      XOR-swizzled LDS, bijective XCD swizzle, PERMUTED-LAYOUT packed C store,
//      fused el/er epilogue. (R15-proven: 105-108 us) ----
__global__ __launch_bounds__(256) void k_gemm(const __bf16* __restrict__ A,
                                              const __bf16* __restrict__ BT,
                                              __bf16* __restrict__ C,
                                              const float* __restrict__ al,
                                              const float* __restrict__ ar,
                                              __bf16* __restrict__ el,
                                              __bf16* __restrict__ er, int M, int K) {
  __shared__ alignas(16) __bf16 lds[2][2][128 * 64];
  int t = threadIdx.x, l = t & 63, w = t >> 6;
  int nwg = gridDim.x, q8 = nwg >> 3, r8 = nwg & 7;
  int xx = blockIdx.x & 7, loc = blockIdx.x >> 3;
  int swz = (xx < r8 ? xx * (q8 + 1) : r8 * (q8 + 1) + (xx - r8) * q8) + loc;
  int m0 = (swz >> 2) * 128, n0 = (swz & 3) * 128;
  int wm = (w >> 1) * 64, wn = (w & 1) * 64;
  f4 acc[4][4] = {};

  const __bf16* pSA[4];
  const __bf16* pSB[4];
#pragma unroll
  for (int u = 0; u < 4; u++) {
    int s = t + u * 256;
    int row = s >> 3, c = s & 7;
    int scol = ((c ^ (row & 7)) * 8);
    int ra = m0 + row; if (ra >= M) ra = M - 1;
    pSA[u] = A + (size_t)ra * K + scol;
    pSB[u] = BT + (size_t)(n0 + row) * K + scol;
  }

#define STG(buf, kk)                                          \
  do {                                                        \
    gload16(pSA[0] + (kk), &lds[buf][0][(t) * 8]);            \
    gload16(pSA[1] + (kk), &lds[buf][0][(t + 256) * 8]);      \
    gload16(pSA[2] + (kk), &lds[buf][0][(t + 512) * 8]);      \
    gload16(pSA[3] + (kk), &lds[buf][0][(t + 768) * 8]);      \
    gload16(pSB[0] + (kk), &lds[buf][1][(t) * 8]);            \
    gload16(pSB[1] + (kk), &lds[buf][1][(t + 256) * 8]);      \
    gload16(pSB[2] + (kk), &lds[buf][1][(t + 512) * 8]);      \
    gload16(pSB[3] + (kk), &lds[buf][1][(t + 768) * 8]);      \
  } while (0)

  int rA[4], rB[4];
#pragma unroll
  for (int i = 0; i < 4; i++) {
    rA[i] = (wm + i * 16 + (l & 15)) * 64;
    rB[i] = (wn + i * 16 + (l & 15)) * 64;
  }
  int ch0 = (l >> 4);

  int nt = K >> 6;  // 8 (K=512) or 4 (K=256)
  STG(0, 0);
  for (int kt = 0; kt < nt; kt++) {
    int cb = kt & 1;
    asm volatile("s_waitcnt vmcnt(0)" ::: "memory");
    __builtin_amdgcn_s_barrier();
    __builtin_amdgcn_sched_barrier(0);
    if (kt + 1 < nt) STG(cb ^ 1, (kt + 1) * 64);
    bf16x8 a[4][2], b[4][2];
#pragma unroll
    for (int ks = 0; ks < 2; ks++)
#pragma unroll
      for (int i = 0; i < 4; i++) {
        int ch = ks * 4 + ch0;
        int rowA7 = (rA[i] >> 6) & 7;
        int rowB7 = (rB[i] >> 6) & 7;
        a[i][ks] = *(const bf16x8*)(&lds[cb][0][rA[i] + ((ch ^ rowA7) * 8)]);
        b[i][ks] = *(const bf16x8*)(&lds[cb][1][rB[i] + ((ch ^ rowB7) * 8)]);
      }
#pragma unroll
    for (int ks = 0; ks < 2; ks++)
#pragma unroll
      for (int i = 0; i < 4; i++)
#pragma unroll
        for (int j = 0; j < 4; j++)
          acc[i][j] = __builtin_amdgcn_mfma_f32_16x16x32_bf16(a[i][ks], b[j][ks], acc[i][j], 0, 0, 0);
  }
#undef STG

  // ---- C write: packed bf16x4, permuted layout (stored col' = (c*4+j) for phys c+16j) ----
  int rbase = m0 + wm + (l >> 4) * 4;
  int cbase = n0 + wn + (l & 15) * 4;
#pragma unroll
  for (int i = 0; i < 4; i++)
#pragma unroll
    for (int q2 = 0; q2 < 4; q2++) {
      int row = rbase + i * 16 + q2;
      if (row < M) {
        bf16x4 o = {(__bf16)acc[i][0][q2], (__bf16)acc[i][1][q2],
                    (__bf16)acc[i][2][q2], (__bf16)acc[i][3][q2]};
        *(bf16x4*)(&C[(size_t)row * FDIM + cbase]) = o;
      }
    }

  // ---- fused el/er (bf16 out): in-register, phys al/ar — layout-invariant ----
  int h = (n0 + wn) >> 6;
  float av[4], bv[4];
#pragma unroll
  for (int j = 0; j < 4; j++) {
    av[j] = al[h * 64 + j * 16 + (l & 15)];
    bv[j] = ar[h * 64 + j * 16 + (l & 15)];
  }
#pragma unroll
  for (int i = 0; i < 4; i++)
#pragma unroll
    for (int q2 = 0; q2 < 4; q2++) {
      float se = acc[i][0][q2] * av[0] + acc[i][1][q2] * av[1] +
                 acc[i][2][q2] * av[2] + acc[i][3][q2] * av[3];
      float sr = acc[i][0][q2] * bv[0] + acc[i][1][q2] * bv[1] +
                 acc[i][2][q2] * bv[2] + acc[i][3][q2] * bv[3];
      se += __shfl_xor(se, 1); se += __shfl_xor(se, 2);
      se += __shfl_xor(se, 4); se += __shfl_xor(se, 8);
      sr += __shfl_xor(sr, 1); sr += __shfl_xor(sr, 2);
      sr += __shfl_xor(sr, 4); sr += __shfl_xor(sr, 8);
      if ((l & 15) == 0) {
        int row = rbase + i * 16 + q2;
        if (row < M) {
          el[row * NH + h] = (__bf16)se;
          er[row * NH + h] = (__bf16)sr;
        }
      }
    }
}

// ---- CSR build ----
__global__ void k_count(const int* __restrict__ dst, int* __restrict__ deg) {
  int e = blockIdx.x * 256 + threadIdx.x;
  int r = blockIdx.y;
  if (e < NEDGE) {
    int d = dst[(size_t)r * NEDGE + e];
    if ((unsigned)d < (unsigned)NNODES) atomicAdd(&deg[r * NNODES + d], 1);
  }
}

__global__ __launch_bounds__(256) void k_scan_a(const int* __restrict__ in, int* __restrict__ out,
                                                int* __restrict__ bsum, int n) {
  __shared__ int wsums[4];
  int t = threadIdx.x, lane = t & 63, w = t >> 6;
  int base = blockIdx.x * 1024 + t * 4;
  int v0 = base + 0 < n ? in[base + 0] : 0;
  int v1 = base + 1 < n ? in[base + 1] : 0;
  int v2 = base + 2 < n ? in[base + 2] : 0;
  int v3 = base + 3 < n ? in[base + 3] : 0;
  int tot = v0 + v1 + v2 + v3;
  int sc = tot;
#pragma unroll
  for (int off = 1; off < 64; off <<= 1) {
    int u = __shfl_up(sc, off);
    if (lane >= off) sc += u;
  }
  if (lane == 63) wsums[w] = sc;
  __syncthreads();
  int add = 0;
#pragma unroll
  for (int i = 0; i < 4; i++)
    if (i < w) add += wsums[i];
  int excl = add + sc - tot;
  if (base + 0 < n) out[base + 0] = excl;
  if (base + 1 < n) out[base + 1] = excl + v0;
  if (base + 2 < n) out[base + 2] = excl + v0 + v1;
  if (base + 3 < n) out[base + 3] = excl + v0 + v1 + v2;
  if (t == 255) bsum[blockIdx.x] = add + sc;
}

__global__ __launch_bounds__(256) void k_scan_b(int* __restrict__ bsum, int nb) {
  __shared__ int wsums[4];
  int t = threadIdx.x, lane = t & 63, w = t >> 6;
  int i0 = t * 2, i1 = t * 2 + 1;
  int v0 = i0 < nb ? bsum[i0] : 0;
  int v1 = i1 < nb ? bsum[i1] : 0;
  int tot = v0 + v1, sc = tot;
#pragma unroll
  for (int off = 1; off < 64; off <<= 1) {
    int u = __shfl_up(sc, off);
    if (lane >= off) sc += u;
  }
  if (lane == 63) wsums[w] = sc;
  __syncthreads();
  int add = 0;
#pragma unroll
  for (int i = 0; i < 4; i++)
    if (i < w) add += wsums[i];
  int excl = add + sc - tot;
  if (i0 < nb) bsum[i0] = excl;
  if (i1 < nb) bsum[i1] = excl + v0;
}

__global__ void k_scan_c(int* __restrict__ out, const int* __restrict__ bsum, int n) {
  int i = blockIdx.x * 256 + threadIdx.x;
  if (i < n) out[i] += bsum[i >> 10];
}

__global__ void k_scatter(const int* __restrict__ src, const int* __restrict__ dst,
                          const int* __restrict__ ptrf, int* __restrict__ cur,
                          int* __restrict__ csrc) {
  int e = blockIdx.x * 256 + threadIdx.x;
  int r = blockIdx.y;
  if (e >= NEDGE) return;
  int d = dst[(size_t)r * NEDGE + e];
  if ((unsigned)d >= (unsigned)NNODES) return;
  int slot = ptrf[r * NNODES + d] + atomicAdd(&cur[r * NNODES + d], 1);
  if ((unsigned)slot < (unsigned)(NREL * NEDGE))
    csrc[slot] = src[(size_t)r * NEDGE + e];
}

// ---- fused segment-softmax + aggregate + ELU, edge-unroll-2; writeMode=1: full write ----
__global__ void k_agg(const __bf16* __restrict__ f, const __bf16* __restrict__ el,
                      const __bf16* __restrict__ er, const int* __restrict__ ptrf,
                      const int* __restrict__ deg, const int* __restrict__ csrc,
                      __bf16* __restrict__ accG, int writeMode) {
  int t = threadIdx.x;
  int l = t & 63;
  int d = blockIdx.x * 4 + (t >> 6);
  int h = l >> 3;
  int cnt = deg[d];
  float res[8] = {0.f, 0.f, 0.f, 0.f, 0.f, 0.f, 0.f, 0.f};
  if (cnt > 0) {
    int start = ptrf[d];
    if (start < 0) start = 0;
    if (start > NREL * NEDGE) start = NREL * NEDGE;
    if (cnt > NREL * NEDGE - start) cnt = NREL * NEDGE - start;
    const int* cp = csrc + start;
    const __bf16* elh = el + h;
    float erh = (float)er[d * NH + h];
    float a0[8] = {0.f, 0.f, 0.f, 0.f, 0.f, 0.f, 0.f, 0.f};
    float a1[8] = {0.f, 0.f, 0.f, 0.f, 0.f, 0.f, 0.f, 0.f};
    float den = 0.f;
    int j = 0;
    for (; j + 1 < cnt; j += 2) {
      int s0 = cp[j], s1 = cp[j + 1];
      if ((unsigned)s0 >= (unsigned)NNODES) s0 = 0;
      if ((unsigned)s1 >= (unsigned)NNODES) s1 = 0;
      bf16x8 fv0 = *(const bf16x8*)(f + (size_t)s0 * FDIM + l * 8);
      bf16x8 fv1 = *(const bf16x8*)(f + (size_t)s1 * FDIM + l * 8);
      float e0 = (float)elh[s0 * NH] + erh;
      float e1 = (float)elh[s1 * NH] + erh;
      e0 = (e0 > 0.f) ? e0 : 0.2f * e0;
      e1 = (e1 > 0.f) ? e1 : 0.2f * e1;
      float ex0 = __expf(e0), ex1 = __expf(e1);
      den += ex0 + ex1;
#pragma unroll
      for (int i = 0; i < 8; i++) {
        a0[i] += ex0 * (float)fv0[i];
        a1[i] += ex1 * (float)fv1[i];
      }
    }
    if (j < cnt) {
      int s0 = cp[j];
      if ((unsigned)s0 >= (unsigned)NNODES) s0 = 0;
      bf16x8 fv0 = *(const bf16x8*)(f + (size_t)s0 * FDIM + l * 8);
      float e0 = (float)elh[s0 * NH] + erh;
      e0 = (e0 > 0.f) ? e0 : 0.2f * e0;
      float ex0 = __expf(e0);
      den += ex0;
#pragma unroll
      for (int i = 0; i < 8; i++) a0[i] += ex0 * (float)fv0[i];
    }
    float inv = 1.f / (den + 1e-9f);
#pragma unroll
    for (int i = 0; i < 8; i++) res[i] = eluf((a0[i] + a1[i]) * inv);
  } else if (!writeMode) {
    return;
  }
  __bf16* ap = accG + (size_t)d * FDIM + l * 8;
  bf16x8 o;
  if (writeMode) {
#pragma unroll
    for (int i = 0; i < 8; i++) o[i] = (__bf16)res[i];
  } else {
    bf16x8 cv = *(bf16x8*)ap;
#pragma unroll
    for (int i = 0; i < 8; i++) o[i] = (__bf16)((float)cv[i] + res[i]);
  }
  *(bf16x8*)ap = o;
}

// ---- layer-2 agg + fused head-mean; un-permutes at final out write (packed f2) ----
__global__ void k_aggm(const __bf16* __restrict__ f, const __bf16* __restrict__ el,
                       const __bf16* __restrict__ er, const int* __restrict__ ptrf,
                       const int* __restrict__ deg, const int* __restrict__ csrc,
                       float* __restrict__ out, int writeMode) {
  int t = threadIdx.x;
  int l = t & 63;
  int d = blockIdx.x * 4 + (t >> 6);
  int h = l >> 3;
  int cnt = deg[d];
  float res[8] = {0.f, 0.f, 0.f, 0.f, 0.f, 0.f, 0.f, 0.f};
  if (cnt > 0) {
    int start = ptrf[d];
    if (start < 0) start = 0;
    if (start > NREL * NEDGE) start = NREL * NEDGE;
    if (cnt > NREL * NEDGE - start) cnt = NREL * NEDGE - start;
    const int* cp = csrc + start;
    const __bf16* elh = el + h;
    float erh = (float)er[d * NH + h];
    float a0[8] = {0.f, 0.f, 0.f, 0.f, 0.f, 0.f, 0.f, 0.f};
    float a1[8] = {0.f, 0.f, 0.f, 0.f, 0.f, 0.f, 0.f, 0.f};
    float den = 0.f;
    int j = 0;
    for (; j + 1 < cnt; j += 2) {
      int s0 = cp[j], s1 = cp[j + 1];
      if ((unsigned)s0 >= (unsigned)NNODES) s0 = 0;
      if ((unsigned)s1 >= (unsigned)NNODES) s1 = 0;
      bf16x8 fv0 = *(const bf16x8*)(f + (size_t)s0 * FDIM + l * 8);
      bf16x8 fv1 = *(const bf16x8*)(f + (size_t)s1 * FDIM + l * 8);
      float e0 = (float)elh[s0 * NH] + erh;
      float e1 = (float)elh[s1 * NH] + erh;
      e0 = (e0 > 0.f) ? e0 : 0.2f * e0;
      e1 = (e1 > 0.f) ? e1 : 0.2f * e1;
      float ex0 = __expf(e0), ex1 = __expf(e1);
      den += ex0 + ex1;
#pragma unroll
      for (int i = 0; i < 8; i++) {
        a0[i] += ex0 * (float)fv0[i];
        a1[i] += ex1 * (float)fv1[i];
      }
    }
    if (j < cnt) {
      int s0 = cp[j];
      if ((unsigned)s0 >= (unsigned)NNODES) s0 = 0;
      bf16x8 fv0 = *(const bf16x8*)(f + (size_t)s0 * FDIM + l * 8);
      float e0 = (float)elh[s0 * NH] + erh;
      e0 = (e0 > 0.f) ? e0 : 0.2f * e0;
      float ex0 = __expf(e0);
      den += ex0;
#pragma unroll
      for (int i = 0; i < 8; i++) a0[i] += ex0 * (float)fv0[i];
    }
    float inv = 1.f / (den + 1e-9f);
#pragma unroll
    for (int i = 0; i < 8; i++) res[i] = eluf((a0[i] + a1[i]) * inv);
  }
  // cross-head sum (heads are bits 3-5 of l; within-head position in stored space)
#pragma unroll
  for (int i = 0; i < 8; i++) {
    res[i] += __shfl_xor(res[i], 8);
    res[i] += __shfl_xor(res[i], 16);
    res[i] += __shfl_xor(res[i], 32);
  }
  if (l < 8) {
    // lane l holds stored cols sw = l*8+i -> phys p = (sw>>2) + (sw&3)*16.
    // For i in {4m, 4m+1, 4m+2, 4m+3}: p = {2l+16m ... } -> phys pairs (2l, 2l+1) per m.
    // res index for phys (2l + 16m): sw = ... inverse: sw = (p&15)*4 + (p>>4) with
    // p = 2l+16m -> sw = (2l)*4 + m = 8l + m?? (only if 2l<16, l<8 ✓). phys 2l+1+16m -> sw = 8l+4+m.
    float* op = out + (size_t)d * 64;
#pragma unroll
    for (int m = 0; m < 4; m++) {
      f2 v = {res[m] * 0.125f, res[4 + m] * 0.125f};  // phys cols (2l+16m, 2l+1+16m)
      if (writeMode) *(f2*)(op + 2 * l + 16 * m) = v;
      else {
        f2 c = *(f2*)(op + 2 * l + 16 * m);
        *(f2*)(op + 2 * l + 16 * m) = c + v;
      }
    }
  }
}

// ---- host ----
extern "C" void kernel_launch(void* const* d_in, const int* in_sizes, int n_in,
                              void* d_out, int out_size, void* d_ws, size_t ws_size,
                              hipStream_t stream) {
  const float* x = (const float*)d_in[0];
  const int* srcp = (const int*)d_in[1];
  const int* dstp = (const int*)d_in[2];
  const float* Wl[3]  = {(const float*)d_in[3], (const float*)d_in[6], (const float*)d_in[9]};
  const float* alp[3] = {(const float*)d_in[4], (const float*)d_in[7], (const float*)d_in[10]};
  const float* arl[3] = {(const float*)d_in[5], (const float*)d_in[8], (const float*)d_in[11]};
  float* out = (float*)d_out;
  (void)in_sizes; (void)n_in; (void)out_size;

  auto rup = [](size_t b) { return (b + 255) & ~(size_t)255; };
  size_t need = 3 * rup((size_t)NNODES * FDIM * 2) +
                2 * rup((size_t)NNODES * NH * 2) +
                rup((size_t)NREL * FDIM * FDIM * 2) +
                2 * rup((size_t)NREL * NNODES * 4) +
                rup((size_t)NREL * NEDGE * 4);
  if (ws_size < need) return;

  char* ws = (char*)d_ws;
  size_t off = 0;
  auto alloc = [&](size_t bytes) -> void* { void* p = ws + off; off += rup(bytes); return p; };
  __bf16* b0   = (__bf16*)alloc((size_t)NNODES * FDIM * 2);
  __bf16* b1   = (__bf16*)alloc((size_t)NNODES * FDIM * 2);
  __bf16* fbuf = (__bf16*)alloc((size_t)NNODES * FDIM * 2);
  __bf16* el   = (__bf16*)alloc((size_t)NNODES * NH * 2);
  __bf16* er   = (__bf16*)alloc((size_t)NNODES * NH * 2);
  __bf16* Wt   = (__bf16*)alloc((size_t)NREL * FDIM * FDIM * 2);
  int* deg  = (int*)alloc((size_t)NREL * NNODES * 4);
  int* ptrf = (int*)alloc((size_t)NREL * NNODES * 4);
  int* csrc = (int*)alloc((size_t)NREL * NEDGE * 4);
  int* cur  = (int*)fbuf;  // aliased (dead during CSR build)
  int* bsum = (int*)((char*)fbuf + rup((size_t)NREL * NNODES * 4));

  // ---- CSR by dst ----
  hipMemsetAsync(deg, 0, (size_t)NREL * NNODES * 4, stream);
  hipMemsetAsync(cur, 0, (size_t)NREL * NNODES * 4, stream);
  k_count<<<dim3((NEDGE + 255) / 256, NREL), 256, 0, stream>>>(dstp, deg);
  int ntot = NREL * NNODES;
  int nb1 = (ntot + 1023) / 1024;
  k_scan_a<<<nb1, 256, 0, stream>>>(deg, ptrf, bsum, ntot);
  k_scan_b<<<1, 256, 0, stream>>>(bsum, nb1);
  k_scan_c<<<(ntot + 255) / 256, 256, 0, stream>>>(ptrf, bsum, ntot);
  k_scatter<<<dim3((NEDGE + 255) / 256, NREL), 256, 0, stream>>>(srcp, dstp, ptrf, cur, csrc);

  // layer-0 input: conv x -> b1 as [N,256] bf16 (natural col order)
  k_conv<<<(NNODES * 256) / 1024, 256, 0, stream>>>(x, b1);

  int ngrid = NMB * 4;  // 3128 (128x128 tiles over [100000, 512])
  for (int L = 0; L < 3; L++) {
    int K = (L == 0) ? 256 : FDIM;
    const __bf16* inb = (L == 1) ? b0 : b1;  // L0:b1(x), L1:b0, L2:b1
    __bf16* outb = (L == 0) ? b0 : b1;       // L2 writes d_out instead
    k_transW<<<dim3(K / 32, 16, NREL), dim3(32, 8), 0, stream>>>(Wl[L], Wt, K, L > 0 ? 1 : 0);
    for (int r = 0; r < NREL; r++) {
      k_gemm<<<ngrid, 256, 0, stream>>>(inb, Wt + (size_t)r * FDIM * K, fbuf,
                                        alp[L] + (size_t)r * 512,
                                        arl[L] + (size_t)r * 512,
                                        el, er, NNODES, K);
      if (L < 2)
        k_agg<<<NNODES / 4, 256, 0, stream>>>(fbuf, el, er, ptrf + (size_t)r * NNODES,
                                              deg + (size_t)r * NNODES, csrc, outb,
                                              r == 0 ? 1 : 0);
      else
        k_aggm<<<NNODES / 4, 256, 0, stream>>>(fbuf, el, er, ptrf + (size_t)r * NNODES,
                                               deg + (size_t)r * NNODES, csrc, out,
                                               r == 0 ? 1 : 0);
    }
  }
}